// Round 1
// baseline (692.807 us; speedup 1.0000x reference)
//
#include <hip/hip_runtime.h>
#include <hip/hip_bf16.h>
#include <stdint.h>

// LeviCivitaKAN: c = pp@lw^T + x@w1^T; LN(c)*gamma+beta
//   pp[b,p] = xs[b,idx_i[p]] * xs[b,idx_j[p]],  xs = (x - translation)/scale
// Strategy: bf16 MFMA GEMM with concatenated K (4096 pairs + 1024 base), fp32 accum.
//   k0: Wcat[o][0:4096]=lw, [4096:5120]=w1  (bf16)
//   k1: per row: xs in LDS, pp -> bf16, bf16(x) appended  => Xcat[r][5120] bf16
//   k2: C = Xcat @ Wcat^T  (m97 128x128-tile structure, 16x16x32 bf16 MFMA,
//       global_load_lds width=16, 2-barrier K-loop, XCD swizzle)
//   k3: in-place LayerNorm on d_out

#define IN_F 1024
#define OUT_F 1024
#define N_PAIRS 4096
#define BATCH_N 32768
#define KTOT (N_PAIRS + IN_F)   // 5120
#define EPS_LN 1e-5f

typedef __attribute__((ext_vector_type(8))) __bf16 bf16x8;
typedef __attribute__((ext_vector_type(4))) float f32x4;

__device__ __forceinline__ unsigned short f32_to_bf16_bits(float f) {
  union { float f; unsigned u; } c; c.f = f;
  unsigned r = c.u + 0x7FFFu + ((c.u >> 16) & 1u);   // round-to-nearest-even
  return (unsigned short)(r >> 16);
}

// ---------------- k0: weight concat + fp32->bf16 ----------------
__global__ __launch_bounds__(256) void prep_w_kernel(
    const float* __restrict__ lw, const float* __restrict__ w1,
    unsigned short* __restrict__ Wcat) {
  int t = blockIdx.x * 256 + threadIdx.x;   // one thread per 4 elems
  int e = t * 4;
  int o = e / KTOT;
  int k = e - o * KTOT;
  const float* src = (k < N_PAIRS) ? (lw + (size_t)o * N_PAIRS + k)
                                   : (w1 + (size_t)o * IN_F + (k - N_PAIRS));
  float4 v = *reinterpret_cast<const float4*>(src);
  ushort4 b;
  b.x = f32_to_bf16_bits(v.x);
  b.y = f32_to_bf16_bits(v.y);
  b.z = f32_to_bf16_bits(v.z);
  b.w = f32_to_bf16_bits(v.w);
  *reinterpret_cast<ushort4*>(Wcat + e) = b;
}

// ---------------- k1: per-row pp + bf16(x) -> Xcat ----------------
__global__ __launch_bounds__(256) void prep_x_kernel(
    const float* __restrict__ x,
    const int* __restrict__ idx_i, const int* __restrict__ idx_j,
    const float* __restrict__ scale, const float* __restrict__ translation,
    unsigned short* __restrict__ Xcat,   // [chunk][KTOT]
    int rowBase) {
  __shared__ float xs[IN_F];
  int r = blockIdx.x;
  int t = threadIdx.x;
  const float* xrow = x + (size_t)(rowBase + r) * IN_F;
  float4 xv = reinterpret_cast<const float4*>(xrow)[t];
  float4 sv = reinterpret_cast<const float4*>(scale)[t];
  float4 tv = reinterpret_cast<const float4*>(translation)[t];
  float4 xsv;
  xsv.x = (xv.x - tv.x) / sv.x;
  xsv.y = (xv.y - tv.y) / sv.y;
  xsv.z = (xv.z - tv.z) / sv.z;
  xsv.w = (xv.w - tv.w) / sv.w;
  reinterpret_cast<float4*>(xs)[t] = xsv;

  unsigned short* rowout = Xcat + (size_t)r * KTOT;
  ushort4 xb;
  xb.x = f32_to_bf16_bits(xv.x);
  xb.y = f32_to_bf16_bits(xv.y);
  xb.z = f32_to_bf16_bits(xv.z);
  xb.w = f32_to_bf16_bits(xv.w);
  *reinterpret_cast<ushort4*>(rowout + N_PAIRS + t * 4) = xb;

  __syncthreads();
#pragma unroll
  for (int g = 0; g < 2; ++g) {
    int p = (g * 256 + t) * 8;
    int4 ia = *reinterpret_cast<const int4*>(idx_i + p);
    int4 ib = *reinterpret_cast<const int4*>(idx_i + p + 4);
    int4 ja = *reinterpret_cast<const int4*>(idx_j + p);
    int4 jb = *reinterpret_cast<const int4*>(idx_j + p + 4);
    ushort4 oa, ob;
    oa.x = f32_to_bf16_bits(xs[ia.x] * xs[ja.x]);
    oa.y = f32_to_bf16_bits(xs[ia.y] * xs[ja.y]);
    oa.z = f32_to_bf16_bits(xs[ia.z] * xs[ja.z]);
    oa.w = f32_to_bf16_bits(xs[ia.w] * xs[ja.w]);
    ob.x = f32_to_bf16_bits(xs[ib.x] * xs[jb.x]);
    ob.y = f32_to_bf16_bits(xs[ib.y] * xs[jb.y]);
    ob.z = f32_to_bf16_bits(xs[ib.z] * xs[jb.z]);
    ob.w = f32_to_bf16_bits(xs[ib.w] * xs[jb.w]);
    *reinterpret_cast<ushort4*>(rowout + p) = oa;
    *reinterpret_cast<ushort4*>(rowout + p + 4) = ob;
  }
}

// ---------------- k2: bf16 GEMM C = A @ Bw^T (m97 structure) ----------------
#define BM 128
#define BN 128
#define BK 64

__device__ __forceinline__ void gload_lds16(const void* g, void* l) {
  __builtin_amdgcn_global_load_lds(
      (const __attribute__((address_space(1))) void*)g,
      (__attribute__((address_space(3))) void*)l, 16, 0, 0);
}

__global__ __launch_bounds__(256) void gemm_kernel(
    const unsigned short* __restrict__ A,    // [Mc][KTOT] bf16 bits
    const unsigned short* __restrict__ Bw,   // [OUT_F][KTOT] bf16 bits
    float* __restrict__ C) {                 // [Mc][OUT_F]
  __shared__ __align__(16) unsigned short As[BM * BK];
  __shared__ __align__(16) unsigned short Bs[BN * BK];

  // XCD-aware swizzle (nwg is always a multiple of 8 here)
  int nwg = gridDim.x;
  int bid = blockIdx.x;
  int cpx = nwg >> 3;
  int swz = (bid & 7) * cpx + (bid >> 3);
  const int nct = OUT_F / BN;   // 8
  int rt = swz / nct;
  int ct = swz - rt * nct;

  int tid = threadIdx.x;
  int lane = tid & 63;
  int wid = tid >> 6;
  int wr = wid >> 1;            // 2x2 wave grid, each wave 64x64
  int wc = wid & 1;

  const unsigned short* Abase = A + (size_t)rt * BM * KTOT;
  const unsigned short* Bbase = Bw + (size_t)ct * BN * KTOT;

  f32x4 acc[4][4];
#pragma unroll
  for (int m = 0; m < 4; ++m)
#pragma unroll
    for (int n = 0; n < 4; ++n)
      acc[m][n] = {0.f, 0.f, 0.f, 0.f};

  int r0 = tid >> 3;              // 0..31: row within 32-row issue chunk
  int c0 = (tid & 7) << 3;        // bf16 col offset, 8-elem granules
  char* AsB = (char*)As;
  char* BsB = (char*)Bs;
  int ldsOff = wid * 1024;        // wave-uniform LDS base within 4KB chunk

  for (int k0 = 0; k0 < KTOT; k0 += BK) {
    __syncthreads();              // previous tile's ds_reads done
#pragma unroll
    for (int i = 0; i < 4; ++i)
      gload_lds16(Abase + (size_t)(i * 32 + r0) * KTOT + k0 + c0,
                  AsB + i * 4096 + ldsOff);
#pragma unroll
    for (int i = 0; i < 4; ++i)
      gload_lds16(Bbase + (size_t)(i * 32 + r0) * KTOT + k0 + c0,
                  BsB + i * 4096 + ldsOff);
    __syncthreads();              // vmcnt(0) drain + barrier
#pragma unroll
    for (int kk = 0; kk < 2; ++kk) {
      bf16x8 af[4], bfr[4];
      int kb = kk * 64 + ((lane >> 4) << 4);   // byte offset in K
#pragma unroll
      for (int m = 0; m < 4; ++m) {
        int row = wr * 64 + m * 16 + (lane & 15);
        af[m] = *reinterpret_cast<const bf16x8*>(AsB + row * (BK * 2) + kb);
      }
#pragma unroll
      for (int n = 0; n < 4; ++n) {
        int row = wc * 64 + n * 16 + (lane & 15);
        bfr[n] = *reinterpret_cast<const bf16x8*>(BsB + row * (BK * 2) + kb);
      }
#pragma unroll
      for (int m = 0; m < 4; ++m)
#pragma unroll
        for (int n = 0; n < 4; ++n)
          acc[m][n] = __builtin_amdgcn_mfma_f32_16x16x32_bf16(
              af[m], bfr[n], acc[m][n], 0, 0, 0);
    }
  }

  // epilogue: C row = base + (lane>>4)*4 + j, col = base + (lane&15)
  int crow0 = rt * BM + wr * 64 + ((lane >> 4) << 2);
  int ccol0 = ct * BN + wc * 64 + (lane & 15);
#pragma unroll
  for (int m = 0; m < 4; ++m)
#pragma unroll
    for (int n = 0; n < 4; ++n)
#pragma unroll
      for (int j = 0; j < 4; ++j)
        C[(size_t)(crow0 + m * 16 + j) * OUT_F + ccol0 + n * 16] = acc[m][n][j];
}

// ---------------- k3: in-place LayerNorm over d_out rows ----------------
__global__ __launch_bounds__(256) void ln_kernel(
    float* __restrict__ C, const float* __restrict__ gamma,
    const float* __restrict__ beta) {
  int r = blockIdx.x;
  int t = threadIdx.x;
  float* row = C + (size_t)r * OUT_F;
  float4 v = reinterpret_cast<const float4*>(row)[t];
  float s = v.x + v.y + v.z + v.w;
  float s2 = v.x * v.x + v.y * v.y + v.z * v.z + v.w * v.w;
#pragma unroll
  for (int off = 32; off > 0; off >>= 1) {
    s += __shfl_down(s, off, 64);
    s2 += __shfl_down(s2, off, 64);
  }
  __shared__ float ps[4], ps2[4];
  int lane = t & 63, wid = t >> 6;
  if (lane == 0) { ps[wid] = s; ps2[wid] = s2; }
  __syncthreads();
  float fs = ps[0] + ps[1] + ps[2] + ps[3];
  float fs2 = ps2[0] + ps2[1] + ps2[2] + ps2[3];
  float mu = fs * (1.0f / OUT_F);
  float var = fs2 * (1.0f / OUT_F) - mu * mu;
  float rstd = rsqrtf(var + EPS_LN);
  float4 g = reinterpret_cast<const float4*>(gamma)[t];
  float4 b = reinterpret_cast<const float4*>(beta)[t];
  float4 o;
  o.x = (v.x - mu) * rstd * g.x + b.x;
  o.y = (v.y - mu) * rstd * g.y + b.y;
  o.z = (v.z - mu) * rstd * g.z + b.z;
  o.w = (v.w - mu) * rstd * g.w + b.w;
  reinterpret_cast<float4*>(row)[t] = o;
}

// ---------------- launch ----------------
extern "C" void kernel_launch(void* const* d_in, const int* in_sizes, int n_in,
                              void* d_out, int out_size, void* d_ws, size_t ws_size,
                              hipStream_t stream) {
  const float* x           = (const float*)d_in[0];
  const int*   idx_i       = (const int*)d_in[1];
  const int*   idx_j       = (const int*)d_in[2];
  const float* scale       = (const float*)d_in[3];
  const float* translation = (const float*)d_in[4];
  const float* lw          = (const float*)d_in[5];
  const float* w1          = (const float*)d_in[6];
  const float* gamma       = (const float*)d_in[7];
  const float* beta        = (const float*)d_in[8];
  float* out = (float*)d_out;

  unsigned short* Wcat = (unsigned short*)d_ws;
  size_t wcat_bytes = (size_t)OUT_F * KTOT * 2;          // 10.5 MB
  unsigned short* Xcat = (unsigned short*)((char*)d_ws + wcat_bytes);
  size_t avail = ws_size > wcat_bytes ? ws_size - wcat_bytes : 0;

  int chunk = BATCH_N;                                   // rows per pass
  while (chunk > 512 && (size_t)chunk * KTOT * 2 > avail) chunk >>= 1;

  prep_w_kernel<<<dim3(OUT_F * KTOT / 4 / 256), dim3(256), 0, stream>>>(lw, w1, Wcat);

  for (int rb = 0; rb < BATCH_N; rb += chunk) {
    prep_x_kernel<<<dim3(chunk), dim3(256), 0, stream>>>(
        x, idx_i, idx_j, scale, translation, Xcat, rb);
    gemm_kernel<<<dim3((chunk / BM) * (OUT_F / BN)), dim3(256), 0, stream>>>(
        Xcat, Wcat, out + (size_t)rb * OUT_F);
  }

  ln_kernel<<<dim3(BATCH_N), dim3(256), 0, stream>>>(out, gamma, beta);
}

// Round 2
// 490.727 us; speedup vs baseline: 1.4118x; 1.4118x over previous
//
#include <hip/hip_runtime.h>
#include <hip/hip_bf16.h>
#include <stdint.h>

// LeviCivitaKAN: c = pp@lw^T + x@w1^T; LN(c)*gamma+beta
// bf16 MFMA GEMM, concatenated K (4096 pairs + 1024 base) = 5120.
// GEMM v2: 256x256 tile, 8 waves, BK=32, 4-slot LDS ring, counted-vmcnt
// deep pipeline (T3+T4), T2 source+read XOR swizzle, T1 XCD swizzle, T5 setprio.

#define IN_F 1024
#define OUT_F 1024
#define N_PAIRS 4096
#define BATCH_N 32768
#define KTOT (N_PAIRS + IN_F)   // 5120
#define EPS_LN 1e-5f

#define BM 256
#define BN 256
#define BK 32
#define NT (KTOT / BK)          // 160
#define SLOT_BYTES 32768        // A 16KB + B 16KB
#define B_OFF 16384

typedef __attribute__((ext_vector_type(8))) __bf16 bf16x8;
typedef __attribute__((ext_vector_type(4))) float f32x4;

__device__ __forceinline__ unsigned short f32_to_bf16_bits(float f) {
  union { float f; unsigned u; } c; c.f = f;
  unsigned r = c.u + 0x7FFFu + ((c.u >> 16) & 1u);   // RNE
  return (unsigned short)(r >> 16);
}

__device__ __forceinline__ void gload_lds16(const void* g, void* l) {
  __builtin_amdgcn_global_load_lds(
      (const __attribute__((address_space(1))) void*)g,
      (__attribute__((address_space(3))) void*)l, 16, 0, 0);
}

// ---------------- k0: weight concat + fp32->bf16 ----------------
__global__ __launch_bounds__(256) void prep_w_kernel(
    const float* __restrict__ lw, const float* __restrict__ w1,
    unsigned short* __restrict__ Wcat) {
  int t = blockIdx.x * 256 + threadIdx.x;
  int e = t * 4;
  int o = e / KTOT;
  int k = e - o * KTOT;
  const float* src = (k < N_PAIRS) ? (lw + (size_t)o * N_PAIRS + k)
                                   : (w1 + (size_t)o * IN_F + (k - N_PAIRS));
  float4 v = *reinterpret_cast<const float4*>(src);
  ushort4 b;
  b.x = f32_to_bf16_bits(v.x);
  b.y = f32_to_bf16_bits(v.y);
  b.z = f32_to_bf16_bits(v.z);
  b.w = f32_to_bf16_bits(v.w);
  *reinterpret_cast<ushort4*>(Wcat + e) = b;
}

// ---------------- k1: per-row pp + bf16(x) -> Xcat ----------------
__global__ __launch_bounds__(256) void prep_x_kernel(
    const float* __restrict__ x,
    const int* __restrict__ idx_i, const int* __restrict__ idx_j,
    const float* __restrict__ scale, const float* __restrict__ translation,
    unsigned short* __restrict__ Xcat, int rowBase) {
  __shared__ float xs[IN_F];
  int r = blockIdx.x;
  int t = threadIdx.x;
  const float* xrow = x + (size_t)(rowBase + r) * IN_F;
  float4 xv = reinterpret_cast<const float4*>(xrow)[t];
  float4 sv = reinterpret_cast<const float4*>(scale)[t];
  float4 tv = reinterpret_cast<const float4*>(translation)[t];
  float4 xsv;
  xsv.x = (xv.x - tv.x) / sv.x;
  xsv.y = (xv.y - tv.y) / sv.y;
  xsv.z = (xv.z - tv.z) / sv.z;
  xsv.w = (xv.w - tv.w) / sv.w;
  reinterpret_cast<float4*>(xs)[t] = xsv;

  unsigned short* rowout = Xcat + (size_t)r * KTOT;
  ushort4 xb;
  xb.x = f32_to_bf16_bits(xv.x);
  xb.y = f32_to_bf16_bits(xv.y);
  xb.z = f32_to_bf16_bits(xv.z);
  xb.w = f32_to_bf16_bits(xv.w);
  *reinterpret_cast<ushort4*>(rowout + N_PAIRS + t * 4) = xb;

  __syncthreads();
#pragma unroll
  for (int g = 0; g < 2; ++g) {
    int p = (g * 256 + t) * 8;
    int4 ia = *reinterpret_cast<const int4*>(idx_i + p);
    int4 ib = *reinterpret_cast<const int4*>(idx_i + p + 4);
    int4 ja = *reinterpret_cast<const int4*>(idx_j + p);
    int4 jb = *reinterpret_cast<const int4*>(idx_j + p + 4);
    ushort4 oa, ob;
    oa.x = f32_to_bf16_bits(xs[ia.x] * xs[ja.x]);
    oa.y = f32_to_bf16_bits(xs[ia.y] * xs[ja.y]);
    oa.z = f32_to_bf16_bits(xs[ia.z] * xs[ja.z]);
    oa.w = f32_to_bf16_bits(xs[ia.w] * xs[ja.w]);
    ob.x = f32_to_bf16_bits(xs[ib.x] * xs[jb.x]);
    ob.y = f32_to_bf16_bits(xs[ib.y] * xs[jb.y]);
    ob.z = f32_to_bf16_bits(xs[ib.z] * xs[jb.z]);
    ob.w = f32_to_bf16_bits(xs[ib.w] * xs[jb.w]);
    *reinterpret_cast<ushort4*>(rowout + p) = oa;
    *reinterpret_cast<ushort4*>(rowout + p + 4) = ob;
  }
}

// ---------------- k2: bf16 GEMM C = A @ Bw^T, deep-pipelined ----------------
// LDS slot layout (linear, global_load_lds dest): A [256 rows][64 B], B same at +16KB.
// T2 swizzle: data at LDS (row, cb) = global (row, cb ^ ((row>>1 & 3)<<4));
// read applies the same XOR -> uniform 2-way bank access (free).
__global__ __launch_bounds__(512, 2) void gemm_kernel(
    const unsigned short* __restrict__ A,    // [Mc][KTOT] bf16 bits
    const unsigned short* __restrict__ Bw,   // [OUT_F][KTOT] bf16 bits
    float* __restrict__ C) {                 // [Mc][OUT_F] fp32
  __shared__ __align__(16) char lds[4 * SLOT_BYTES];   // 128 KiB ring

  int nwg = gridDim.x;                 // multiple of 8
  int bid = blockIdx.x;
  int cpx = nwg >> 3;
  int swz = (bid & 7) * cpx + (bid >> 3);   // XCD-aware (T1)
  int rt = swz >> 2;                   // OUT_F/BN = 4 col tiles
  int ct = swz & 3;

  int tid = threadIdx.x;
  int lane = tid & 63;
  int w = tid >> 6;                    // 0..7
  int wr = w >> 2;                     // 0..1  (M half)
  int wc = w & 3;                      // 0..3  (N quarter)

  const char* Ab = (const char*)(A + (size_t)rt * BM * KTOT);
  const char* Bb = (const char*)(Bw + (size_t)ct * BN * KTOT);
  const size_t rs = (size_t)KTOT * 2;  // row stride bytes

  // staging: lane covers row = i*128 + w*16 + (lane>>2), dest cb = (lane&3)*16
  int src_cb = ((lane & 3) << 4) ^ (((lane >> 3) & 3) << 4);  // inverse swizzle
  int srow = w * 16 + (lane >> 2);
  char* ldsw = lds + w * 1024;         // wave-uniform base (+slot, +i*8192, +B_OFF)

  f32x4 acc[8][4];
#pragma unroll
  for (int m = 0; m < 8; ++m)
#pragma unroll
    for (int n = 0; n < 4; ++n) acc[m][n] = {0.f, 0.f, 0.f, 0.f};

  // prologue: stage tiles 0,1,2 -- per-tile fences keep vmcnt issue order valid
#pragma unroll
  for (int u = 0; u < 3; ++u) {
    char* sb = ldsw + u * SLOT_BYTES;
#pragma unroll
    for (int i = 0; i < 2; ++i) {
      gload_lds16(Ab + (size_t)u * (BK * 2) + (size_t)(i * 128 + srow) * rs + src_cb,
                  sb + i * 8192);
      gload_lds16(Bb + (size_t)u * (BK * 2) + (size_t)(i * 128 + srow) * rs + src_cb,
                  sb + B_OFF + i * 8192);
    }
    asm volatile("" ::: "memory");
  }

  int lane15 = lane & 15;
  int kb = ((lane >> 4) << 4) ^ (((lane15 >> 1) & 3) << 4);   // swizzled K-byte
  const char* arow0 = lds + (wr * 128 + lane15) * 64 + kb;
  const char* brow0 = lds + B_OFF + (wc * 64 + lane15) * 64 + kb;

#pragma unroll 4
  for (int t = 0; t < NT; ++t) {
    // T4: counted vmcnt -- tiles t+1, t+2 (8 loads/wave) stay in flight
    if (t + 2 < NT)      asm volatile("s_waitcnt vmcnt(8)" ::: "memory");
    else if (t + 1 < NT) asm volatile("s_waitcnt vmcnt(4)" ::: "memory");
    else                 asm volatile("s_waitcnt vmcnt(0)" ::: "memory");
    __builtin_amdgcn_s_barrier();      // raw barrier: no vmcnt drain
    asm volatile("" ::: "memory");

    if (t + 3 < NT) {                  // prefetch into slot freed at this barrier
      int u = t + 3;
      char* sb = ldsw + (u & 3) * SLOT_BYTES;
#pragma unroll
      for (int i = 0; i < 2; ++i) {
        gload_lds16(Ab + (size_t)u * (BK * 2) + (size_t)(i * 128 + srow) * rs + src_cb,
                    sb + i * 8192);
        gload_lds16(Bb + (size_t)u * (BK * 2) + (size_t)(i * 128 + srow) * rs + src_cb,
                    sb + B_OFF + i * 8192);
      }
    }

    int so = (t & 3) * SLOT_BYTES;
    bf16x8 af[8], bf[4];
#pragma unroll
    for (int m = 0; m < 8; ++m)
      af[m] = *(const bf16x8*)(arow0 + so + m * (16 * 64));
#pragma unroll
    for (int n = 0; n < 4; ++n)
      bf[n] = *(const bf16x8*)(brow0 + so + n * (16 * 64));

    __builtin_amdgcn_s_setprio(1);     // T5
#pragma unroll
    for (int m = 0; m < 8; ++m)
#pragma unroll
      for (int n = 0; n < 4; ++n)
        acc[m][n] = __builtin_amdgcn_mfma_f32_16x16x32_bf16(
            af[m], bf[n], acc[m][n], 0, 0, 0);
    __builtin_amdgcn_s_setprio(0);
  }

  // epilogue: C row = (lane>>4)*4 + j, col = lane&15 (m89 layout)
  int crow0 = rt * BM + wr * 128 + ((lane >> 4) << 2);
  int ccol0 = ct * BN + wc * 64 + lane15;
#pragma unroll
  for (int m = 0; m < 8; ++m)
#pragma unroll
    for (int n = 0; n < 4; ++n)
#pragma unroll
      for (int j = 0; j < 4; ++j)
        C[(size_t)(crow0 + m * 16 + j) * OUT_F + ccol0 + n * 16] = acc[m][n][j];
}

// ---------------- k3: in-place LayerNorm over d_out rows ----------------
__global__ __launch_bounds__(256) void ln_kernel(
    float* __restrict__ C, const float* __restrict__ gamma,
    const float* __restrict__ beta) {
  int r = blockIdx.x;
  int t = threadIdx.x;
  float* row = C + (size_t)r * OUT_F;
  float4 v = reinterpret_cast<const float4*>(row)[t];
  float s = v.x + v.y + v.z + v.w;
  float s2 = v.x * v.x + v.y * v.y + v.z * v.z + v.w * v.w;
#pragma unroll
  for (int off = 32; off > 0; off >>= 1) {
    s += __shfl_down(s, off, 64);
    s2 += __shfl_down(s2, off, 64);
  }
  __shared__ float ps[4], ps2[4];
  int lane = t & 63, wid = t >> 6;
  if (lane == 0) { ps[wid] = s; ps2[wid] = s2; }
  __syncthreads();
  float fs = ps[0] + ps[1] + ps[2] + ps[3];
  float fs2 = ps2[0] + ps2[1] + ps2[2] + ps2[3];
  float mu = fs * (1.0f / OUT_F);
  float var = fs2 * (1.0f / OUT_F) - mu * mu;
  float rstd = rsqrtf(var + EPS_LN);
  float4 g = reinterpret_cast<const float4*>(gamma)[t];
  float4 b = reinterpret_cast<const float4*>(beta)[t];
  float4 o;
  o.x = (v.x - mu) * rstd * g.x + b.x;
  o.y = (v.y - mu) * rstd * g.y + b.y;
  o.z = (v.z - mu) * rstd * g.z + b.z;
  o.w = (v.w - mu) * rstd * g.w + b.w;
  reinterpret_cast<float4*>(row)[t] = o;
}

// ---------------- launch ----------------
extern "C" void kernel_launch(void* const* d_in, const int* in_sizes, int n_in,
                              void* d_out, int out_size, void* d_ws, size_t ws_size,
                              hipStream_t stream) {
  const float* x           = (const float*)d_in[0];
  const int*   idx_i       = (const int*)d_in[1];
  const int*   idx_j       = (const int*)d_in[2];
  const float* scale       = (const float*)d_in[3];
  const float* translation = (const float*)d_in[4];
  const float* lw          = (const float*)d_in[5];
  const float* w1          = (const float*)d_in[6];
  const float* gamma       = (const float*)d_in[7];
  const float* beta        = (const float*)d_in[8];
  float* out = (float*)d_out;

  unsigned short* Wcat = (unsigned short*)d_ws;
  size_t wcat_bytes = (size_t)OUT_F * KTOT * 2;          // 10.5 MB
  unsigned short* Xcat = (unsigned short*)((char*)d_ws + wcat_bytes);
  size_t avail = ws_size > wcat_bytes ? ws_size - wcat_bytes : 0;

  int chunk = BATCH_N;                                   // rows per pass
  while (chunk > 512 && (size_t)chunk * KTOT * 2 > avail) chunk >>= 1;

  prep_w_kernel<<<dim3(OUT_F * KTOT / 4 / 256), dim3(256), 0, stream>>>(lw, w1, Wcat);

  for (int rb = 0; rb < BATCH_N; rb += chunk) {
    prep_x_kernel<<<dim3(chunk), dim3(256), 0, stream>>>(
        x, idx_i, idx_j, scale, translation, Xcat, rb);
    gemm_kernel<<<dim3((chunk / BM) * (OUT_F / BN)), dim3(512), 0, stream>>>(
        Xcat, Wcat, out + (size_t)rb * OUT_F);
  }

  ln_kernel<<<dim3(BATCH_N), dim3(256), 0, stream>>>(out, gamma, beta);
}

// Round 5
// 446.022 us; speedup vs baseline: 1.5533x; 1.1002x over previous
//
#include <hip/hip_runtime.h>
#include <hip/hip_bf16.h>
#include <stdint.h>

// LeviCivitaKAN: c = pp@lw^T + x@w1^T; LN(c)*gamma+beta
// bf16 MFMA GEMM, concatenated K (4096 pairs + 1024 base) = 5120.
// GEMM v3b: m201-style phased schedule. 256x256 tile, 8 waves, BK=64,
// 2-deep double buffer (128 KiB), 4 phases/K-tile (16 MFMA each),
// counted vmcnt(6) placed BEFORE P4's END barrier so the barrier certifies
// next-tile data landed for ALL waves (fixes R4 race), T2 XOR swizzle,
// T1 XCD swizzle, T5 setprio.

#define IN_F 1024
#define OUT_F 1024
#define N_PAIRS 4096
#define BATCH_N 32768
#define KTOT (N_PAIRS + IN_F)   // 5120
#define EPS_LN 1e-5f

#define BM 256
#define BN 256
#define BK 64
#define NKT (KTOT / BK)         // 80 K-tiles
#define RS ((size_t)KTOT * 2)   // global row stride bytes

typedef __attribute__((ext_vector_type(8))) __bf16 bf16x8;
typedef __attribute__((ext_vector_type(4))) float f32x4;

__device__ __forceinline__ unsigned short f32_to_bf16_bits(float f) {
  union { float f; unsigned u; } c; c.f = f;
  unsigned r = c.u + 0x7FFFu + ((c.u >> 16) & 1u);   // RNE
  return (unsigned short)(r >> 16);
}

__device__ __forceinline__ void gload_lds16(const void* g, void* l) {
  __builtin_amdgcn_global_load_lds(
      (const __attribute__((address_space(1))) void*)g,
      (__attribute__((address_space(3))) void*)l, 16, 0, 0);
}

// ---------------- k0: weight concat + fp32->bf16 ----------------
__global__ __launch_bounds__(256) void prep_w_kernel(
    const float* __restrict__ lw, const float* __restrict__ w1,
    unsigned short* __restrict__ Wcat) {
  int t = blockIdx.x * 256 + threadIdx.x;
  int e = t * 4;
  int o = e / KTOT;
  int k = e - o * KTOT;
  const float* src = (k < N_PAIRS) ? (lw + (size_t)o * N_PAIRS + k)
                                   : (w1 + (size_t)o * IN_F + (k - N_PAIRS));
  float4 v = *reinterpret_cast<const float4*>(src);
  ushort4 b;
  b.x = f32_to_bf16_bits(v.x);
  b.y = f32_to_bf16_bits(v.y);
  b.z = f32_to_bf16_bits(v.z);
  b.w = f32_to_bf16_bits(v.w);
  *reinterpret_cast<ushort4*>(Wcat + e) = b;
}

// ---------------- k1: per-row pp + bf16(x) -> Xcat ----------------
__global__ __launch_bounds__(256) void prep_x_kernel(
    const float* __restrict__ x,
    const int* __restrict__ idx_i, const int* __restrict__ idx_j,
    const float* __restrict__ scale, const float* __restrict__ translation,
    unsigned short* __restrict__ Xcat, int rowBase) {
  __shared__ float xs[IN_F];
  int r = blockIdx.x;
  int t = threadIdx.x;
  const float* xrow = x + (size_t)(rowBase + r) * IN_F;
  float4 xv = reinterpret_cast<const float4*>(xrow)[t];
  float4 sv = reinterpret_cast<const float4*>(scale)[t];
  float4 tv = reinterpret_cast<const float4*>(translation)[t];
  float4 xsv;
  xsv.x = (xv.x - tv.x) / sv.x;
  xsv.y = (xv.y - tv.y) / sv.y;
  xsv.z = (xv.z - tv.z) / sv.z;
  xsv.w = (xv.w - tv.w) / sv.w;
  reinterpret_cast<float4*>(xs)[t] = xsv;

  unsigned short* rowout = Xcat + (size_t)r * KTOT;
  ushort4 xb;
  xb.x = f32_to_bf16_bits(xv.x);
  xb.y = f32_to_bf16_bits(xv.y);
  xb.z = f32_to_bf16_bits(xv.z);
  xb.w = f32_to_bf16_bits(xv.w);
  *reinterpret_cast<ushort4*>(rowout + N_PAIRS + t * 4) = xb;

  __syncthreads();
#pragma unroll
  for (int g = 0; g < 2; ++g) {
    int p = (g * 256 + t) * 8;
    int4 ia = *reinterpret_cast<const int4*>(idx_i + p);
    int4 ib = *reinterpret_cast<const int4*>(idx_i + p + 4);
    int4 ja = *reinterpret_cast<const int4*>(idx_j + p);
    int4 jb = *reinterpret_cast<const int4*>(idx_j + p + 4);
    ushort4 oa, ob;
    oa.x = f32_to_bf16_bits(xs[ia.x] * xs[ja.x]);
    oa.y = f32_to_bf16_bits(xs[ia.y] * xs[ja.y]);
    oa.z = f32_to_bf16_bits(xs[ia.z] * xs[ja.z]);
    oa.w = f32_to_bf16_bits(xs[ia.w] * xs[ja.w]);
    ob.x = f32_to_bf16_bits(xs[ib.x] * xs[jb.x]);
    ob.y = f32_to_bf16_bits(xs[ib.y] * xs[jb.y]);
    ob.z = f32_to_bf16_bits(xs[ib.z] * xs[jb.z]);
    ob.w = f32_to_bf16_bits(xs[ib.w] * xs[jb.w]);
    *reinterpret_cast<ushort4*>(rowout + p) = oa;
    *reinterpret_cast<ushort4*>(rowout + p + 4) = ob;
  }
}

// ---------------- k2: bf16 GEMM, phased ----------------
// LDS per parity (64 KiB): regions rg: 0=B0(rows0-127) 1=B1(128-255)
// 2=A0(0-127) 3=A1(128-255), each 16 KiB, row stride 128 B,
// kb_lds = kb ^ ((row&7)<<4).  Half-tile h: kt=h>>2, rg=h&3.
// Stage points: P1 issues h=4kt+7, P2: +8, P3: +9, P4: +10.
// Tile kt+1 readiness: vmcnt before P4 END barrier (6 loads = 3 half-tiles
// in flight in steady state; 0 at the capped tail).

#define STAGE_HALF(h_)                                                        \
  {                                                                           \
    int h__ = (h_);                                                           \
    if (h__ < 4 * NKT) {                                                      \
      int kt__ = h__ >> 2, rg__ = h__ & 3;                                    \
      const char* mb__ = (rg__ < 2) ? Bb : Ab;                                \
      const char* src__ = mb__ + (size_t)((rg__ & 1) * 128 + srow) * RS +     \
                          (size_t)kt__ * 128 + skb;                           \
      char* dst__ = lds + ((kt__ & 1) << 16) + (rg__ << 14) + (w << 10);      \
      gload_lds16(src__, dst__);                                              \
      gload_lds16(src__ + (size_t)64 * RS, dst__ + 8192);                     \
    }                                                                         \
  }

#define PHASE_SYNC()                                                          \
  __builtin_amdgcn_sched_barrier(0);                                          \
  __builtin_amdgcn_s_barrier();                                               \
  asm volatile("s_waitcnt lgkmcnt(0)" ::: "memory");                          \
  __builtin_amdgcn_sched_barrier(0);

#define PHASE_END()                                                           \
  __builtin_amdgcn_sched_barrier(0);                                          \
  __builtin_amdgcn_s_barrier();                                               \
  __builtin_amdgcn_sched_barrier(0);

#define MFMA_PAIR(mb)                                                         \
  __builtin_amdgcn_s_setprio(1);                                              \
  _Pragma("unroll") for (int i_ = 0; i_ < 2; ++i_)                            \
      _Pragma("unroll") for (int n_ = 0; n_ < 4; ++n_) {                      \
    acc[(mb) + i_][n_] = __builtin_amdgcn_mfma_f32_16x16x32_bf16(             \
        am[(mb) + i_][0], bfr[n_][0], acc[(mb) + i_][n_], 0, 0, 0);           \
    acc[(mb) + i_][n_] = __builtin_amdgcn_mfma_f32_16x16x32_bf16(             \
        am[(mb) + i_][1], bfr[n_][1], acc[(mb) + i_][n_], 0, 0, 0);           \
  }                                                                           \
  __builtin_amdgcn_s_setprio(0);

__global__ __launch_bounds__(512, 2) void gemm_kernel(
    const unsigned short* __restrict__ A,    // [Mc][KTOT] bf16 bits
    const unsigned short* __restrict__ Bw,   // [OUT_F][KTOT] bf16 bits
    float* __restrict__ C) {                 // [Mc][OUT_F] fp32
  __shared__ __align__(16) char lds[131072];

  int nwg = gridDim.x;                 // multiple of 8
  int bid = blockIdx.x;
  int cpx = nwg >> 3;
  int swz = (bid & 7) * cpx + (bid >> 3);   // T1 XCD swizzle
  int rt = swz >> 2;                   // OUT_F/BN = 4 col tiles
  int ct = swz & 3;

  int tid = threadIdx.x;
  int lane = tid & 63;
  int w = tid >> 6;                    // 0..7
  int wr = w >> 2;                     // 0..1
  int wc = w & 3;                      // 0..3

  const char* Ab = (const char*)A + (size_t)rt * BM * RS;
  const char* Bb = (const char*)Bw + (size_t)ct * BN * RS;

  // staging geometry: lane l of wave w covers row w*8 + (l>>3), cols 16B
  int srow = tid >> 3;                                   // 0..63
  int skb = ((tid & 7) << 4) ^ (((tid >> 3) & 7) << 4);  // inverse swizzle

  // read-side geometry
  int lane15 = lane & 15;
  int cb = lane >> 4;
  int swzm = (lane15 & 7) << 4;
  int kb0 = (cb << 4) ^ swzm;          // ks=0 swizzled K-byte
  int kb1 = (64 + (cb << 4)) ^ swzm;   // ks=1
  const char* aRow = lds + 32768 + (wr * 128 + lane15) * 128;
  const char* bRow = lds + (wc * 64 + lane15) * 128;

  f32x4 acc[8][4];
#pragma unroll
  for (int m = 0; m < 8; ++m)
#pragma unroll
    for (int n = 0; n < 4; ++n) acc[m][n] = {0.f, 0.f, 0.f, 0.f};

  // prologue: stage half-tiles 0..6, issue order pinned; then certify tile 0
#pragma unroll
  for (int hp = 0; hp < 7; ++hp) {
    STAGE_HALF(hp);
    __builtin_amdgcn_sched_barrier(0);
  }
  asm volatile("s_waitcnt vmcnt(6)" ::: "memory");   // tile 0 (4 half-tiles) landed
  __builtin_amdgcn_s_barrier();                      // ... for ALL waves
  __builtin_amdgcn_sched_barrier(0);

  for (int kt = 0; kt < NKT; ++kt) {
    int bo = (kt & 1) << 16;
    bf16x8 bfr[4][2], am[8][2];

    // ---- P1: read all B (8) + A m0-1; stage (kt+1,A1); MFMA m0-1 ----
#pragma unroll
    for (int n = 0; n < 4; ++n) {
      bfr[n][0] = *(const bf16x8*)(bRow + bo + n * 2048 + kb0);
      bfr[n][1] = *(const bf16x8*)(bRow + bo + n * 2048 + kb1);
    }
#pragma unroll
    for (int m = 0; m < 2; ++m) {
      am[m][0] = *(const bf16x8*)(aRow + bo + m * 2048 + kb0);
      am[m][1] = *(const bf16x8*)(aRow + bo + m * 2048 + kb1);
    }
    STAGE_HALF(4 * kt + 7);
    PHASE_SYNC();
    MFMA_PAIR(0);
    PHASE_END();

    // ---- P2: read A m2-3; stage (kt+2,B0); MFMA m2-3 ----
#pragma unroll
    for (int m = 2; m < 4; ++m) {
      am[m][0] = *(const bf16x8*)(aRow + bo + m * 2048 + kb0);
      am[m][1] = *(const bf16x8*)(aRow + bo + m * 2048 + kb1);
    }
    STAGE_HALF(4 * kt + 8);
    PHASE_SYNC();
    MFMA_PAIR(2);
    PHASE_END();

    // ---- P3: read A m4-7; stage (kt+2,B1); MFMA m4-5 ----
#pragma unroll
    for (int m = 4; m < 8; ++m) {
      am[m][0] = *(const bf16x8*)(aRow + bo + m * 2048 + kb0);
      am[m][1] = *(const bf16x8*)(aRow + bo + m * 2048 + kb1);
    }
    STAGE_HALF(4 * kt + 9);
    PHASE_SYNC();
    MFMA_PAIR(4);
    PHASE_END();

    // ---- P4: stage (kt+2,A0); MFMA m6-7; certify tile kt+1 before END ----
    STAGE_HALF(4 * kt + 10);
    PHASE_SYNC();
    MFMA_PAIR(6);
    __builtin_amdgcn_sched_barrier(0);
    if (kt + 2 < NKT) {          // steady state: 3 half-tiles in flight
      asm volatile("s_waitcnt vmcnt(6)" ::: "memory");
    } else if (kt + 1 < NKT) {   // tail: staging capped, drain fully
      asm volatile("s_waitcnt vmcnt(0)" ::: "memory");
    }
    __builtin_amdgcn_s_barrier();
    __builtin_amdgcn_sched_barrier(0);
  }

  // epilogue: C row = (lane>>4)*4 + j, col = lane&15 (m89 layout)
  int crow0 = rt * BM + wr * 128 + (cb << 2);
  int ccol0 = ct * BN + wc * 64 + lane15;
#pragma unroll
  for (int m = 0; m < 8; ++m)
#pragma unroll
    for (int n = 0; n < 4; ++n)
#pragma unroll
      for (int j = 0; j < 4; ++j)
        C[(size_t)(crow0 + m * 16 + j) * OUT_F + ccol0 + n * 16] = acc[m][n][j];
}

// ---------------- k3: in-place LayerNorm over d_out rows ----------------
__global__ __launch_bounds__(256) void ln_kernel(
    float* __restrict__ C, const float* __restrict__ gamma,
    const float* __restrict__ beta) {
  int r = blockIdx.x;
  int t = threadIdx.x;
  float* row = C + (size_t)r * OUT_F;
  float4 v = reinterpret_cast<const float4*>(row)[t];
  float s = v.x + v.y + v.z + v.w;
  float s2 = v.x * v.x + v.y * v.y + v.z * v.z + v.w * v.w;
#pragma unroll
  for (int off = 32; off > 0; off >>= 1) {
    s += __shfl_down(s, off, 64);
    s2 += __shfl_down(s2, off, 64);
  }
  __shared__ float ps[4], ps2[4];
  int lane = t & 63, wid = t >> 6;
  if (lane == 0) { ps[wid] = s; ps2[wid] = s2; }
  __syncthreads();
  float fs = ps[0] + ps[1] + ps[2] + ps[3];
  float fs2 = ps2[0] + ps2[1] + ps2[2] + ps2[3];
  float mu = fs * (1.0f / OUT_F);
  float var = fs2 * (1.0f / OUT_F) - mu * mu;
  float rstd = rsqrtf(var + EPS_LN);
  float4 g = reinterpret_cast<const float4*>(gamma)[t];
  float4 b = reinterpret_cast<const float4*>(beta)[t];
  float4 o;
  o.x = (v.x - mu) * rstd * g.x + b.x;
  o.y = (v.y - mu) * rstd * g.y + b.y;
  o.z = (v.z - mu) * rstd * g.z + b.z;
  o.w = (v.w - mu) * rstd * g.w + b.w;
  reinterpret_cast<float4*>(row)[t] = o;
}

// ---------------- launch ----------------
extern "C" void kernel_launch(void* const* d_in, const int* in_sizes, int n_in,
                              void* d_out, int out_size, void* d_ws, size_t ws_size,
                              hipStream_t stream) {
  const float* x           = (const float*)d_in[0];
  const int*   idx_i       = (const int*)d_in[1];
  const int*   idx_j       = (const int*)d_in[2];
  const float* scale       = (const float*)d_in[3];
  const float* translation = (const float*)d_in[4];
  const float* lw          = (const float*)d_in[5];
  const float* w1          = (const float*)d_in[6];
  const float* gamma       = (const float*)d_in[7];
  const float* beta        = (const float*)d_in[8];
  float* out = (float*)d_out;

  unsigned short* Wcat = (unsigned short*)d_ws;
  size_t wcat_bytes = (size_t)OUT_F * KTOT * 2;          // 10.5 MB
  unsigned short* Xcat = (unsigned short*)((char*)d_ws + wcat_bytes);
  size_t avail = ws_size > wcat_bytes ? ws_size - wcat_bytes : 0;

  int chunk = BATCH_N;                                   // rows per pass
  while (chunk > 512 && (size_t)chunk * KTOT * 2 > avail) chunk >>= 1;

  prep_w_kernel<<<dim3(OUT_F * KTOT / 4 / 256), dim3(256), 0, stream>>>(lw, w1, Wcat);

  for (int rb = 0; rb < BATCH_N; rb += chunk) {
    prep_x_kernel<<<dim3(chunk), dim3(256), 0, stream>>>(
        x, idx_i, idx_j, scale, translation, Xcat, rb);
    gemm_kernel<<<dim3((chunk / BM) * (OUT_F / BN)), dim3(512), 0, stream>>>(
        Xcat, Wcat, out + (size_t)rb * OUT_F);
  }

  ln_kernel<<<dim3(BATCH_N), dim3(256), 0, stream>>>(out, gamma, beta);
}

// Round 6
// 425.974 us; speedup vs baseline: 1.6264x; 1.0471x over previous
//
#include <hip/hip_runtime.h>
#include <hip/hip_bf16.h>
#include <stdint.h>

// LeviCivitaKAN: c = pp@lw^T + x@w1^T; LN(c)*gamma+beta
// bf16 MFMA GEMM, concatenated K (4096 pairs + 1024 base) = 5120.
// GEMM v4: overlapped schedule, 4 barriers/K-tile. Phases by (m-half,k-half):
// P1=m0-3.k0 P2=m0-3.k1 P3=m4-7.k0 P4=m4-7.k1 (16 MFMA each). Each window:
// lgkm0 -> MFMA(setprio) -> next-phase ds_reads + 1 stage-half -> barrier.
// Reads overlap other waves' MFMA. vmcnt(4) certify before K-tile-end barrier.
// T1 XCD swizzle, T2 XOR swizzle, T5 setprio. C written bf16; LN reads bf16.

#define IN_F 1024
#define OUT_F 1024
#define N_PAIRS 4096
#define BATCH_N 32768
#define KTOT (N_PAIRS + IN_F)   // 5120
#define EPS_LN 1e-5f

#define BM 256
#define BN 256
#define BK 64
#define NKT (KTOT / BK)         // 80 K-tiles
#define RS ((size_t)KTOT * 2)   // global row stride bytes

typedef __attribute__((ext_vector_type(8))) __bf16 bf16x8;
typedef __attribute__((ext_vector_type(4))) float f32x4;

__device__ __forceinline__ unsigned short f32_to_bf16_bits(float f) {
  union { float f; unsigned u; } c; c.f = f;
  unsigned r = c.u + 0x7FFFu + ((c.u >> 16) & 1u);   // RNE
  return (unsigned short)(r >> 16);
}

__device__ __forceinline__ float bf16_bits_to_f32(unsigned short b) {
  union { unsigned u; float f; } c; c.u = ((unsigned)b) << 16;
  return c.f;
}

__device__ __forceinline__ void gload_lds16(const void* g, void* l) {
  __builtin_amdgcn_global_load_lds(
      (const __attribute__((address_space(1))) void*)g,
      (__attribute__((address_space(3))) void*)l, 16, 0, 0);
}

// ---------------- k0: weight concat + fp32->bf16 ----------------
__global__ __launch_bounds__(256) void prep_w_kernel(
    const float* __restrict__ lw, const float* __restrict__ w1,
    unsigned short* __restrict__ Wcat) {
  int t = blockIdx.x * 256 + threadIdx.x;
  int e = t * 4;
  int o = e / KTOT;
  int k = e - o * KTOT;
  const float* src = (k < N_PAIRS) ? (lw + (size_t)o * N_PAIRS + k)
                                   : (w1 + (size_t)o * IN_F + (k - N_PAIRS));
  float4 v = *reinterpret_cast<const float4*>(src);
  ushort4 b;
  b.x = f32_to_bf16_bits(v.x);
  b.y = f32_to_bf16_bits(v.y);
  b.z = f32_to_bf16_bits(v.z);
  b.w = f32_to_bf16_bits(v.w);
  *reinterpret_cast<ushort4*>(Wcat + e) = b;
}

// ---------------- k1: per-row pp + bf16(x) -> Xcat ----------------
__global__ __launch_bounds__(256) void prep_x_kernel(
    const float* __restrict__ x,
    const int* __restrict__ idx_i, const int* __restrict__ idx_j,
    const float* __restrict__ scale, const float* __restrict__ translation,
    unsigned short* __restrict__ Xcat, int rowBase) {
  __shared__ float xs[IN_F];
  int r = blockIdx.x;
  int t = threadIdx.x;
  const float* xrow = x + (size_t)(rowBase + r) * IN_F;
  float4 xv = reinterpret_cast<const float4*>(xrow)[t];
  float4 sv = reinterpret_cast<const float4*>(scale)[t];
  float4 tv = reinterpret_cast<const float4*>(translation)[t];
  float4 xsv;
  xsv.x = (xv.x - tv.x) / sv.x;
  xsv.y = (xv.y - tv.y) / sv.y;
  xsv.z = (xv.z - tv.z) / sv.z;
  xsv.w = (xv.w - tv.w) / sv.w;
  reinterpret_cast<float4*>(xs)[t] = xsv;

  unsigned short* rowout = Xcat + (size_t)r * KTOT;
  ushort4 xb;
  xb.x = f32_to_bf16_bits(xv.x);
  xb.y = f32_to_bf16_bits(xv.y);
  xb.z = f32_to_bf16_bits(xv.z);
  xb.w = f32_to_bf16_bits(xv.w);
  *reinterpret_cast<ushort4*>(rowout + N_PAIRS + t * 4) = xb;

  __syncthreads();
#pragma unroll
  for (int g = 0; g < 2; ++g) {
    int p = (g * 256 + t) * 8;
    int4 ia = *reinterpret_cast<const int4*>(idx_i + p);
    int4 ib = *reinterpret_cast<const int4*>(idx_i + p + 4);
    int4 ja = *reinterpret_cast<const int4*>(idx_j + p);
    int4 jb = *reinterpret_cast<const int4*>(idx_j + p + 4);
    ushort4 oa, ob;
    oa.x = f32_to_bf16_bits(xs[ia.x] * xs[ja.x]);
    oa.y = f32_to_bf16_bits(xs[ia.y] * xs[ja.y]);
    oa.z = f32_to_bf16_bits(xs[ia.z] * xs[ja.z]);
    oa.w = f32_to_bf16_bits(xs[ia.w] * xs[ja.w]);
    ob.x = f32_to_bf16_bits(xs[ib.x] * xs[jb.x]);
    ob.y = f32_to_bf16_bits(xs[ib.y] * xs[jb.y]);
    ob.z = f32_to_bf16_bits(xs[ib.z] * xs[jb.z]);
    ob.w = f32_to_bf16_bits(xs[ib.w] * xs[jb.w]);
    *reinterpret_cast<ushort4*>(rowout + p) = oa;
    *reinterpret_cast<ushort4*>(rowout + p + 4) = ob;
  }
}

// ---------------- k2: bf16 GEMM, overlapped 4-barrier schedule ----------------
// LDS per parity (64 KiB): rg 0=B0(rows0-127) 1=B1 2=A0 3=A1, each 16 KiB,
// row stride 128 B, kb_lds = kb ^ ((row&7)<<4). Half-tile h: kt=h>>2, rg=h&3.
// Stage points (window of kt): W1: A0(kt+1), W2: A1(kt+1), W3: B0(kt+2),
// W4: B1(kt+2). vmcnt(4) before K-tile-end barrier certifies tile kt+1.

#define STAGE_HALF(h_)                                                        \
  {                                                                           \
    int h__ = (h_);                                                           \
    if (h__ < 4 * NKT) {                                                      \
      int kt__ = h__ >> 2, rg__ = h__ & 3;                                    \
      const char* mb__ = (rg__ < 2) ? Bb : Ab;                                \
      const char* src__ = mb__ + (size_t)((rg__ & 1) * 128 + srow) * RS +     \
                          (size_t)kt__ * 128 + skb;                           \
      char* dst__ = lds + ((kt__ & 1) << 16) + (rg__ << 14) + (w << 10);      \
      gload_lds16(src__, dst__);                                              \
      gload_lds16(src__ + (size_t)64 * RS, dst__ + 8192);                     \
    }                                                                         \
  }

#define SB0() __builtin_amdgcn_sched_barrier(0)
#define LGKM0() asm volatile("s_waitcnt lgkmcnt(0)" ::: "memory")

#define MFMA_Q(mb, amv, bv)                                                   \
  __builtin_amdgcn_s_setprio(1);                                              \
  _Pragma("unroll") for (int i_ = 0; i_ < 4; ++i_)                            \
      _Pragma("unroll") for (int n_ = 0; n_ < 4; ++n_)                        \
    acc[(mb) + i_][n_] = __builtin_amdgcn_mfma_f32_16x16x32_bf16(             \
        amv[i_], bv[n_], acc[(mb) + i_][n_], 0, 0, 0);                        \
  __builtin_amdgcn_s_setprio(0);

__global__ __launch_bounds__(512, 2) void gemm_kernel(
    const unsigned short* __restrict__ A,    // [Mc][KTOT] bf16 bits
    const unsigned short* __restrict__ Bw,   // [OUT_F][KTOT] bf16 bits
    unsigned short* __restrict__ Cb) {       // [Mc][OUT_F] bf16 bits
  __shared__ __align__(16) char lds[131072];

  int nwg = gridDim.x;                 // multiple of 8
  int bid = blockIdx.x;
  int cpx = nwg >> 3;
  int swz = (bid & 7) * cpx + (bid >> 3);   // T1 XCD swizzle
  int rt = swz >> 2;                   // OUT_F/BN = 4 col tiles
  int ct = swz & 3;

  int tid = threadIdx.x;
  int lane = tid & 63;
  int w = tid >> 6;                    // 0..7
  int wr = w >> 2;                     // 0..1
  int wc = w & 3;                      // 0..3

  const char* Ab = (const char*)A + (size_t)rt * BM * RS;
  const char* Bb = (const char*)Bw + (size_t)ct * BN * RS;

  // staging geometry
  int srow = tid >> 3;                                   // 0..63
  int skb = ((tid & 7) << 4) ^ (((tid >> 3) & 7) << 4);  // inverse swizzle

  // read-side geometry
  int lane15 = lane & 15;
  int cb = lane >> 4;
  int swzm = (lane15 & 7) << 4;
  int kb0 = (cb << 4) ^ swzm;          // ks=0 swizzled K-byte
  int kb1 = (64 + (cb << 4)) ^ swzm;   // ks=1
  const char* aRow = lds + 32768 + (wr * 128 + lane15) * 128;
  const char* bRow = lds + (wc * 64 + lane15) * 128;

  f32x4 acc[8][4];
#pragma unroll
  for (int m = 0; m < 8; ++m)
#pragma unroll
    for (int n = 0; n < 4; ++n) acc[m][n] = {0.f, 0.f, 0.f, 0.f};

  // prologue: B0(0),B1(0),A0(0),A1(0),B0(1),B1(1) in pinned order
#pragma unroll
  for (int hp = 0; hp < 6; ++hp) {
    STAGE_HALF(hp);
    SB0();
  }
  asm volatile("s_waitcnt vmcnt(4)" ::: "memory");   // tile 0 landed
  __builtin_amdgcn_s_barrier();                      // ... for ALL waves
  SB0();

  for (int kt = 0; kt < NKT; ++kt) {
    int bo = (kt & 1) << 16;
    bf16x8 bf0[4], bf1[4], a0[4], a1[4], a2[4], a3[4];

    // ---- W1: read P1 ops; MFMA m0-3.k0; read P2 ops; stage A0(kt+1) ----
#pragma unroll
    for (int n = 0; n < 4; ++n) bf0[n] = *(const bf16x8*)(bRow + bo + n * 2048 + kb0);
#pragma unroll
    for (int i = 0; i < 4; ++i) a0[i] = *(const bf16x8*)(aRow + bo + i * 2048 + kb0);
    LGKM0();
    SB0();
    MFMA_Q(0, a0, bf0);
#pragma unroll
    for (int n = 0; n < 4; ++n) bf1[n] = *(const bf16x8*)(bRow + bo + n * 2048 + kb1);
#pragma unroll
    for (int i = 0; i < 4; ++i) a1[i] = *(const bf16x8*)(aRow + bo + i * 2048 + kb1);
    STAGE_HALF(4 * (kt + 1) + 2);
    SB0();
    __builtin_amdgcn_s_barrier();
    SB0();

    // ---- W2: MFMA m0-3.k1; read P3 ops; stage A1(kt+1) ----
    LGKM0();
    SB0();
    MFMA_Q(0, a1, bf1);
#pragma unroll
    for (int i = 0; i < 4; ++i) a2[i] = *(const bf16x8*)(aRow + bo + (4 + i) * 2048 + kb0);
    STAGE_HALF(4 * (kt + 1) + 3);
    SB0();
    __builtin_amdgcn_s_barrier();
    SB0();

    // ---- W3: MFMA m4-7.k0; read P4 ops; stage B0(kt+2) ----
    LGKM0();
    SB0();
    MFMA_Q(4, a2, bf0);
#pragma unroll
    for (int i = 0; i < 4; ++i) a3[i] = *(const bf16x8*)(aRow + bo + (4 + i) * 2048 + kb1);
    STAGE_HALF(4 * (kt + 2) + 0);
    SB0();
    __builtin_amdgcn_s_barrier();
    SB0();

    // ---- W4: MFMA m4-7.k1; stage B1(kt+2); certify tile kt+1 ----
    LGKM0();
    SB0();
    MFMA_Q(4, a3, bf1);
    STAGE_HALF(4 * (kt + 2) + 1);
    SB0();
    if (kt + 2 < NKT) {
      asm volatile("s_waitcnt vmcnt(4)" ::: "memory");
    } else if (kt + 1 < NKT) {
      asm volatile("s_waitcnt vmcnt(0)" ::: "memory");
    }
    __builtin_amdgcn_s_barrier();
    SB0();
  }

  // epilogue: C row = (lane>>4)*4 + j, col = lane&15 (m89 layout); bf16 store
  int crow0 = rt * BM + wr * 128 + (cb << 2);
  int ccol0 = ct * BN + wc * 64 + lane15;
#pragma unroll
  for (int m = 0; m < 8; ++m)
#pragma unroll
    for (int n = 0; n < 4; ++n)
#pragma unroll
      for (int j = 0; j < 4; ++j)
        Cb[(size_t)(crow0 + m * 16 + j) * OUT_F + ccol0 + n * 16] =
            f32_to_bf16_bits(acc[m][n][j]);
}

// ---------------- k3: LayerNorm, bf16 C -> fp32 out ----------------
__global__ __launch_bounds__(256) void ln_kernel(
    const unsigned short* __restrict__ Cb, float* __restrict__ out,
    const float* __restrict__ gamma, const float* __restrict__ beta) {
  int r = blockIdx.x;
  int t = threadIdx.x;
  ushort4 u = reinterpret_cast<const ushort4*>(Cb + (size_t)r * OUT_F)[t];
  float4 v;
  v.x = bf16_bits_to_f32(u.x);
  v.y = bf16_bits_to_f32(u.y);
  v.z = bf16_bits_to_f32(u.z);
  v.w = bf16_bits_to_f32(u.w);
  float s = v.x + v.y + v.z + v.w;
  float s2 = v.x * v.x + v.y * v.y + v.z * v.z + v.w * v.w;
#pragma unroll
  for (int off = 32; off > 0; off >>= 1) {
    s += __shfl_down(s, off, 64);
    s2 += __shfl_down(s2, off, 64);
  }
  __shared__ float ps[4], ps2[4];
  int lane = t & 63, wid = t >> 6;
  if (lane == 0) { ps[wid] = s; ps2[wid] = s2; }
  __syncthreads();
  float fs = ps[0] + ps[1] + ps[2] + ps[3];
  float fs2 = ps2[0] + ps2[1] + ps2[2] + ps2[3];
  float mu = fs * (1.0f / OUT_F);
  float var = fs2 * (1.0f / OUT_F) - mu * mu;
  float rstd = rsqrtf(var + EPS_LN);
  float4 g = reinterpret_cast<const float4*>(gamma)[t];
  float4 b = reinterpret_cast<const float4*>(beta)[t];
  float4 o;
  o.x = (v.x - mu) * rstd * g.x + b.x;
  o.y = (v.y - mu) * rstd * g.y + b.y;
  o.z = (v.z - mu) * rstd * g.z + b.z;
  o.w = (v.w - mu) * rstd * g.w + b.w;
  reinterpret_cast<float4*>(out + (size_t)r * OUT_F)[t] = o;
}

// ---------------- launch ----------------
extern "C" void kernel_launch(void* const* d_in, const int* in_sizes, int n_in,
                              void* d_out, int out_size, void* d_ws, size_t ws_size,
                              hipStream_t stream) {
  const float* x           = (const float*)d_in[0];
  const int*   idx_i       = (const int*)d_in[1];
  const int*   idx_j       = (const int*)d_in[2];
  const float* scale       = (const float*)d_in[3];
  const float* translation = (const float*)d_in[4];
  const float* lw          = (const float*)d_in[5];
  const float* w1          = (const float*)d_in[6];
  const float* gamma       = (const float*)d_in[7];
  const float* beta        = (const float*)d_in[8];
  float* out = (float*)d_out;

  unsigned short* Wcat = (unsigned short*)d_ws;
  size_t wcat_bytes = (size_t)OUT_F * KTOT * 2;          // 10.5 MB
  size_t avail = ws_size > wcat_bytes ? ws_size - wcat_bytes : 0;

  // per-chunk: Xcat chunk*KTOT*2 + Cb chunk*OUT_F*2 bytes
  int chunk = BATCH_N;
  while (chunk > 512 && (size_t)chunk * (KTOT * 2 + OUT_F * 2) > avail) chunk >>= 1;

  unsigned short* Cb = (unsigned short*)((char*)d_ws + wcat_bytes);
  unsigned short* Xcat = Cb + (size_t)chunk * OUT_F;

  prep_w_kernel<<<dim3(OUT_F * KTOT / 4 / 256), dim3(256), 0, stream>>>(lw, w1, Wcat);

  for (int rb = 0; rb < BATCH_N; rb += chunk) {
    prep_x_kernel<<<dim3(chunk), dim3(256), 0, stream>>>(
        x, idx_i, idx_j, scale, translation, Xcat, rb);
    gemm_kernel<<<dim3((chunk / BM) * (OUT_F / BN)), dim3(512), 0, stream>>>(
        Xcat, Wcat, Cb);
    ln_kernel<<<dim3(chunk), dim3(256), 0, stream>>>(
        Cb, out + (size_t)rb * OUT_F, gamma, beta);
  }
}

// Round 7
// 418.500 us; speedup vs baseline: 1.6555x; 1.0179x over previous
//
#include <hip/hip_runtime.h>
#include <hip/hip_bf16.h>
#include <stdint.h>

// LeviCivitaKAN: c = pp@lw^T + x@w1^T; LN(c)*gamma+beta
// bf16 MFMA GEMM, concatenated K (4096 pairs + 1024 base) = 5120.
// GEMM v5: overlapped 4-barrier/K-tile schedule, NO hard lgkm fences --
// compiler emits fine-grained counted lgkmcnt so ds_reads interleave with
// the MFMA cluster (m97 finding). kt unrolled x2 (bo compile-time).
// Correctness: every ds_read consumed by an MFMA in its window => window-end
// barrier certifies retirement; staged-data RAW certified by counted vmcnt
// before K-tile-end barrier. T1 XCD swizzle, T2 XOR swizzle, T5 setprio.

#define IN_F 1024
#define OUT_F 1024
#define N_PAIRS 4096
#define BATCH_N 32768
#define KTOT (N_PAIRS + IN_F)   // 5120
#define EPS_LN 1e-5f

#define BM 256
#define BN 256
#define BK 64
#define NKT (KTOT / BK)         // 80 K-tiles
#define RS ((size_t)KTOT * 2)   // global row stride bytes

typedef __attribute__((ext_vector_type(8))) __bf16 bf16x8;
typedef __attribute__((ext_vector_type(4))) float f32x4;

__device__ __forceinline__ unsigned short f32_to_bf16_bits(float f) {
  union { float f; unsigned u; } c; c.f = f;
  unsigned r = c.u + 0x7FFFu + ((c.u >> 16) & 1u);   // RNE
  return (unsigned short)(r >> 16);
}

__device__ __forceinline__ float bf16_bits_to_f32(unsigned short b) {
  union { unsigned u; float f; } c; c.u = ((unsigned)b) << 16;
  return c.f;
}

__device__ __forceinline__ void gload_lds16(const void* g, void* l) {
  __builtin_amdgcn_global_load_lds(
      (const __attribute__((address_space(1))) void*)g,
      (__attribute__((address_space(3))) void*)l, 16, 0, 0);
}

// ---------------- k0: weight concat + fp32->bf16 ----------------
__global__ __launch_bounds__(256) void prep_w_kernel(
    const float* __restrict__ lw, const float* __restrict__ w1,
    unsigned short* __restrict__ Wcat) {
  int t = blockIdx.x * 256 + threadIdx.x;
  int e = t * 4;
  int o = e / KTOT;
  int k = e - o * KTOT;
  const float* src = (k < N_PAIRS) ? (lw + (size_t)o * N_PAIRS + k)
                                   : (w1 + (size_t)o * IN_F + (k - N_PAIRS));
  float4 v = *reinterpret_cast<const float4*>(src);
  ushort4 b;
  b.x = f32_to_bf16_bits(v.x);
  b.y = f32_to_bf16_bits(v.y);
  b.z = f32_to_bf16_bits(v.z);
  b.w = f32_to_bf16_bits(v.w);
  *reinterpret_cast<ushort4*>(Wcat + e) = b;
}

// ---------------- k1: per-row pp + bf16(x) -> Xcat ----------------
__global__ __launch_bounds__(256) void prep_x_kernel(
    const float* __restrict__ x,
    const int* __restrict__ idx_i, const int* __restrict__ idx_j,
    const float* __restrict__ scale, const float* __restrict__ translation,
    unsigned short* __restrict__ Xcat, int rowBase) {
  __shared__ float xs[IN_F];
  int r = blockIdx.x;
  int t = threadIdx.x;
  const float* xrow = x + (size_t)(rowBase + r) * IN_F;
  float4 xv = reinterpret_cast<const float4*>(xrow)[t];
  float4 sv = reinterpret_cast<const float4*>(scale)[t];
  float4 tv = reinterpret_cast<const float4*>(translation)[t];
  float4 xsv;
  xsv.x = (xv.x - tv.x) / sv.x;
  xsv.y = (xv.y - tv.y) / sv.y;
  xsv.z = (xv.z - tv.z) / sv.z;
  xsv.w = (xv.w - tv.w) / sv.w;
  reinterpret_cast<float4*>(xs)[t] = xsv;

  unsigned short* rowout = Xcat + (size_t)r * KTOT;
  ushort4 xb;
  xb.x = f32_to_bf16_bits(xv.x);
  xb.y = f32_to_bf16_bits(xv.y);
  xb.z = f32_to_bf16_bits(xv.z);
  xb.w = f32_to_bf16_bits(xv.w);
  *reinterpret_cast<ushort4*>(rowout + N_PAIRS + t * 4) = xb;

  __syncthreads();
#pragma unroll
  for (int g = 0; g < 2; ++g) {
    int p = (g * 256 + t) * 8;
    int4 ia = *reinterpret_cast<const int4*>(idx_i + p);
    int4 ib = *reinterpret_cast<const int4*>(idx_i + p + 4);
    int4 ja = *reinterpret_cast<const int4*>(idx_j + p);
    int4 jb = *reinterpret_cast<const int4*>(idx_j + p + 4);
    ushort4 oa, ob;
    oa.x = f32_to_bf16_bits(xs[ia.x] * xs[ja.x]);
    oa.y = f32_to_bf16_bits(xs[ia.y] * xs[ja.y]);
    oa.z = f32_to_bf16_bits(xs[ia.z] * xs[ja.z]);
    oa.w = f32_to_bf16_bits(xs[ia.w] * xs[ja.w]);
    ob.x = f32_to_bf16_bits(xs[ib.x] * xs[jb.x]);
    ob.y = f32_to_bf16_bits(xs[ib.y] * xs[jb.y]);
    ob.z = f32_to_bf16_bits(xs[ib.z] * xs[jb.z]);
    ob.w = f32_to_bf16_bits(xs[ib.w] * xs[jb.w]);
    *reinterpret_cast<ushort4*>(rowout + p) = oa;
    *reinterpret_cast<ushort4*>(rowout + p + 4) = ob;
  }
}

// ---------------- k2: bf16 GEMM, overlapped schedule v5 ----------------
// LDS per parity (64 KiB): rg 0=B0(rows0-127) 1=B1 2=A0 3=A1, each 16 KiB,
// row stride 128 B, kb_lds = kb ^ ((row&7)<<4). Half-tile h: kt=h>>2, rg=h&3.
// Stage points (window of kt): W1: A0(kt+1), W2: A1(kt+1), W3: B0(kt+2),
// W4: B1(kt+2). vmcnt(4) before K-tile-end barrier certifies tile kt+1.

#define STAGE_HALF(h_)                                                        \
  {                                                                           \
    int h__ = (h_);                                                           \
    if (h__ < 4 * NKT) {                                                      \
      int kt__ = h__ >> 2, rg__ = h__ & 3;                                    \
      const char* mb__ = (rg__ < 2) ? Bb : Ab;                                \
      const char* src__ = mb__ + (size_t)((rg__ & 1) * 128 + srow) * RS +     \
                          (size_t)kt__ * 128 + skb;                           \
      char* dst__ = lds + ((kt__ & 1) << 16) + (rg__ << 14) + (w << 10);      \
      gload_lds16(src__, dst__);                                              \
      gload_lds16(src__ + (size_t)64 * RS, dst__ + 8192);                     \
    }                                                                         \
  }

#define MFMA_Q(mb, amv, bv)                                                   \
  __builtin_amdgcn_s_setprio(1);                                              \
  _Pragma("unroll") for (int i_ = 0; i_ < 4; ++i_)                            \
      _Pragma("unroll") for (int n_ = 0; n_ < 4; ++n_)                        \
    acc[(mb) + i_][n_] = __builtin_amdgcn_mfma_f32_16x16x32_bf16(             \
        amv[i_], bv[n_], acc[(mb) + i_][n_], 0, 0, 0);                        \
  __builtin_amdgcn_s_setprio(0);

// One K-tile, bo = compile-time buffer byte offset (0 or 65536).
#define KTILE_BODY(ktv, bo)                                                   \
  {                                                                           \
    const int kt_c = (ktv);                                                   \
    bf16x8 bf0[4], bf1[4], a0[4], a1[4], a2[4], a3[4];                        \
    /* W1: reads for m0-3.k0 + m0-3.k1; stage A0(kt+1); MFMA m0-3.k0 */       \
    _Pragma("unroll") for (int n = 0; n < 4; ++n)                             \
        bf0[n] = *(const bf16x8*)(bRow + (bo) + n * 2048 + kb0);              \
    _Pragma("unroll") for (int i = 0; i < 4; ++i)                             \
        a0[i] = *(const bf16x8*)(aRow + (bo) + i * 2048 + kb0);               \
    STAGE_HALF(4 * (kt_c + 1) + 2);                                           \
    MFMA_Q(0, a0, bf0);                                                       \
    _Pragma("unroll") for (int n = 0; n < 4; ++n)                             \
        bf1[n] = *(const bf16x8*)(bRow + (bo) + n * 2048 + kb1);              \
    _Pragma("unroll") for (int i = 0; i < 4; ++i)                             \
        a1[i] = *(const bf16x8*)(aRow + (bo) + i * 2048 + kb1);               \
    __builtin_amdgcn_s_barrier();                                             \
    /* W2: MFMA m0-3.k1; reads m4-7.k0; stage A1(kt+1) */                     \
    MFMA_Q(0, a1, bf1);                                                       \
    _Pragma("unroll") for (int i = 0; i < 4; ++i)                             \
        a2[i] = *(const bf16x8*)(aRow + (bo) + (4 + i) * 2048 + kb0);         \
    STAGE_HALF(4 * (kt_c + 1) + 3);                                           \
    __builtin_amdgcn_s_barrier();                                             \
    /* W3: MFMA m4-7.k0; reads m4-7.k1; stage B0(kt+2) */                     \
    MFMA_Q(4, a2, bf0);                                                       \
    _Pragma("unroll") for (int i = 0; i < 4; ++i)                             \
        a3[i] = *(const bf16x8*)(aRow + (bo) + (4 + i) * 2048 + kb1);         \
    STAGE_HALF(4 * (kt_c + 2) + 0);                                           \
    __builtin_amdgcn_s_barrier();                                             \
    /* W4: MFMA m4-7.k1; stage B1(kt+2); certify tile kt+1 */                 \
    MFMA_Q(4, a3, bf1);                                                       \
    STAGE_HALF(4 * (kt_c + 2) + 1);                                           \
    if (kt_c + 2 < NKT) {                                                     \
      asm volatile("s_waitcnt vmcnt(4)" ::: "memory");                        \
    } else if (kt_c + 1 < NKT) {                                              \
      asm volatile("s_waitcnt vmcnt(0)" ::: "memory");                        \
    }                                                                         \
    __builtin_amdgcn_s_barrier();                                             \
  }

__global__ __launch_bounds__(512, 2) void gemm_kernel(
    const unsigned short* __restrict__ A,    // [Mc][KTOT] bf16 bits
    const unsigned short* __restrict__ Bw,   // [OUT_F][KTOT] bf16 bits
    unsigned short* __restrict__ Cb) {       // [Mc][OUT_F] bf16 bits
  __shared__ __align__(16) char lds[131072];

  int nwg = gridDim.x;                 // multiple of 8
  int bid = blockIdx.x;
  int cpx = nwg >> 3;
  int swz = (bid & 7) * cpx + (bid >> 3);   // T1 XCD swizzle
  int rt = swz >> 2;                   // OUT_F/BN = 4 col tiles
  int ct = swz & 3;

  int tid = threadIdx.x;
  int lane = tid & 63;
  int w = tid >> 6;                    // 0..7
  int wr = w >> 2;                     // 0..1
  int wc = w & 3;                      // 0..3

  const char* Ab = (const char*)A + (size_t)rt * BM * RS;
  const char* Bb = (const char*)Bw + (size_t)ct * BN * RS;

  // staging geometry
  int srow = tid >> 3;                                   // 0..63
  int skb = ((tid & 7) << 4) ^ (((tid >> 3) & 7) << 4);  // inverse swizzle

  // read-side geometry
  int lane15 = lane & 15;
  int cb = lane >> 4;
  int swzm = (lane15 & 7) << 4;
  int kb0 = (cb << 4) ^ swzm;          // ks=0 swizzled K-byte
  int kb1 = (64 + (cb << 4)) ^ swzm;   // ks=1
  const char* aRow = lds + 32768 + (wr * 128 + lane15) * 128;
  const char* bRow = lds + (wc * 64 + lane15) * 128;

  f32x4 acc[8][4];
#pragma unroll
  for (int m = 0; m < 8; ++m)
#pragma unroll
    for (int n = 0; n < 4; ++n) acc[m][n] = {0.f, 0.f, 0.f, 0.f};

  // prologue: B0(0),B1(0),A0(0),A1(0),B0(1),B1(1) in pinned order
#pragma unroll
  for (int hp = 0; hp < 6; ++hp) {
    STAGE_HALF(hp);
    __builtin_amdgcn_sched_barrier(0);
  }
  asm volatile("s_waitcnt vmcnt(4)" ::: "memory");   // tile 0 landed
  __builtin_amdgcn_s_barrier();                      // ... for ALL waves

  for (int kt = 0; kt < NKT; kt += 2) {
    KTILE_BODY(kt, 0);
    KTILE_BODY(kt + 1, 65536);
  }

  // epilogue: C row = (lane>>4)*4 + j, col = lane&15 (m89 layout); bf16 store
  int crow0 = rt * BM + wr * 128 + (cb << 2);
  int ccol0 = ct * BN + wc * 64 + lane15;
#pragma unroll
  for (int m = 0; m < 8; ++m)
#pragma unroll
    for (int n = 0; n < 4; ++n)
#pragma unroll
      for (int j = 0; j < 4; ++j)
        Cb[(size_t)(crow0 + m * 16 + j) * OUT_F + ccol0 + n * 16] =
            f32_to_bf16_bits(acc[m][n][j]);
}

// ---------------- k3: LayerNorm, bf16 C -> fp32 out ----------------
__global__ __launch_bounds__(256) void ln_kernel(
    const unsigned short* __restrict__ Cb, float* __restrict__ out,
    const float* __restrict__ gamma, const float* __restrict__ beta) {
  int r = blockIdx.x;
  int t = threadIdx.x;
  ushort4 u = reinterpret_cast<const ushort4*>(Cb + (size_t)r * OUT_F)[t];
  float4 v;
  v.x = bf16_bits_to_f32(u.x);
  v.y = bf16_bits_to_f32(u.y);
  v.z = bf16_bits_to_f32(u.z);
  v.w = bf16_bits_to_f32(u.w);
  float s = v.x + v.y + v.z + v.w;
  float s2 = v.x * v.x + v.y * v.y + v.z * v.z + v.w * v.w;
#pragma unroll
  for (int off = 32; off > 0; off >>= 1) {
    s += __shfl_down(s, off, 64);
    s2 += __shfl_down(s2, off, 64);
  }
  __shared__ float ps[4], ps2[4];
  int lane = t & 63, wid = t >> 6;
  if (lane == 0) { ps[wid] = s; ps2[wid] = s2; }
  __syncthreads();
  float fs = ps[0] + ps[1] + ps[2] + ps[3];
  float fs2 = ps2[0] + ps2[1] + ps2[2] + ps2[3];
  float mu = fs * (1.0f / OUT_F);
  float var = fs2 * (1.0f / OUT_F) - mu * mu;
  float rstd = rsqrtf(var + EPS_LN);
  float4 g = reinterpret_cast<const float4*>(gamma)[t];
  float4 b = reinterpret_cast<const float4*>(beta)[t];
  float4 o;
  o.x = (v.x - mu) * rstd * g.x + b.x;
  o.y = (v.y - mu) * rstd * g.y + b.y;
  o.z = (v.z - mu) * rstd * g.z + b.z;
  o.w = (v.w - mu) * rstd * g.w + b.w;
  reinterpret_cast<float4*>(out + (size_t)r * OUT_F)[t] = o;
}

// ---------------- launch ----------------
extern "C" void kernel_launch(void* const* d_in, const int* in_sizes, int n_in,
                              void* d_out, int out_size, void* d_ws, size_t ws_size,
                              hipStream_t stream) {
  const float* x           = (const float*)d_in[0];
  const int*   idx_i       = (const int*)d_in[1];
  const int*   idx_j       = (const int*)d_in[2];
  const float* scale       = (const float*)d_in[3];
  const float* translation = (const float*)d_in[4];
  const float* lw          = (const float*)d_in[5];
  const float* w1          = (const float*)d_in[6];
  const float* gamma       = (const float*)d_in[7];
  const float* beta        = (const float*)d_in[8];
  float* out = (float*)d_out;

  unsigned short* Wcat = (unsigned short*)d_ws;
  size_t wcat_bytes = (size_t)OUT_F * KTOT * 2;          // 10.5 MB
  size_t avail = ws_size > wcat_bytes ? ws_size - wcat_bytes : 0;

  // per-chunk: Xcat chunk*KTOT*2 + Cb chunk*OUT_F*2 bytes
  int chunk = BATCH_N;
  while (chunk > 512 && (size_t)chunk * (KTOT * 2 + OUT_F * 2) > avail) chunk >>= 1;

  unsigned short* Cb = (unsigned short*)((char*)d_ws + wcat_bytes);
  unsigned short* Xcat = Cb + (size_t)chunk * OUT_F;

  prep_w_kernel<<<dim3(OUT_F * KTOT / 4 / 256), dim3(256), 0, stream>>>(lw, w1, Wcat);

  for (int rb = 0; rb < BATCH_N; rb += chunk) {
    prep_x_kernel<<<dim3(chunk), dim3(256), 0, stream>>>(
        x, idx_i, idx_j, scale, translation, Xcat, rb);
    gemm_kernel<<<dim3((chunk / BM) * (OUT_F / BN)), dim3(512), 0, stream>>>(
        Xcat, Wcat, Cb);
    ln_kernel<<<dim3(chunk), dim3(256), 0, stream>>>(
        Cb, out + (size_t)rb * OUT_F, gamma, beta);
  }
}